// Round 11
// baseline (222.154 us; speedup 1.0000x reference)
//
#include <hip/hip_runtime.h>
#include <stdint.h>

typedef unsigned short ushort_t;
typedef __bf16 bf16x8 __attribute__((ext_vector_type(8)));
typedef float f32x4 __attribute__((ext_vector_type(4)));

#define T_SEQ 4096
#define D_MODEL 896
#define NSPLIT 4

// Attention LDS strides (u16 units).
#define LSK 136   // 68 dwords/row -> conflict-free b128 reads
#define LSV 72
#define LSP 72
// image sizes in u16: Ks 64*136 = 8704 (17408 B = 17 KB), Vt 128*72 = 9216 (18 KB)
#define KIMG_U16 8704
#define VIMG_U16 9216
#define NIMG 93   // 28 fano chunks + 65 band windows per head

// Fano lines, residues sorted ascending per head
__constant__ int d_LINEMASK[7] = {0x07, 0x19, 0x61, 0x2A, 0x52, 0x4C, 0x34};
__constant__ int d_R[7][3] = {{0,1,2},{0,3,4},{0,5,6},{1,3,5},{1,4,6},{2,3,6},{2,4,5}};

__device__ inline unsigned f2bf(float f) {
    unsigned x = __float_as_uint(f);
    return (x + 0x7fffu + ((x >> 16) & 1u)) >> 16;   // RNE
}
__device__ inline float lo_f(unsigned x) { return __uint_as_float(x << 16); }
__device__ inline float hi_f(unsigned x) { return __uint_as_float(x & 0xFFFF0000u); }

// compacted-index -> key: p -> j = 7*(p/3) + r[p%3]
__device__ inline int jof(int p, int r0, int r1, int r2) {
    int g = p / 3, rs = p - 3 * g;
    return 7 * g + ((rs == 0) ? r0 : (rs == 1) ? r1 : r2);
}

// ---------------------------------------------------------------------------
// fp32 -> bf16 bulk convert, 5 tensors (x, Wq, Wk, Wv, Wo). 8 elem/thread.
// ---------------------------------------------------------------------------
__global__ __launch_bounds__(256)
void cvt5(const float* __restrict__ x,  const float* __restrict__ wq,
          const float* __restrict__ wk, const float* __restrict__ wv,
          const float* __restrict__ wo,
          ushort_t* __restrict__ xb,  ushort_t* __restrict__ wqb,
          ushort_t* __restrict__ wkb, ushort_t* __restrict__ wvb,
          ushort_t* __restrict__ wob) {
    const int ten = blockIdx.y;
    const float* s = (ten == 0) ? x : (ten == 1) ? wq : (ten == 2) ? wk
                   : (ten == 3) ? wv : wo;
    ushort_t* d = (ten == 0) ? xb : (ten == 1) ? wqb : (ten == 2) ? wkb
                : (ten == 3) ? wvb : wob;
    const int n8 = ((ten == 0) ? T_SEQ * D_MODEL : D_MODEL * D_MODEL) >> 3;
    for (int i = blockIdx.x * 256 + threadIdx.x; i < n8; i += gridDim.x * 256) {
        float4 a = ((const float4*)s)[2 * i];
        float4 b = ((const float4*)s)[2 * i + 1];
        uint4 u;
        u.x = f2bf(a.x) | (f2bf(a.y) << 16);
        u.y = f2bf(a.z) | (f2bf(a.w) << 16);
        u.z = f2bf(b.x) | (f2bf(b.y) << 16);
        u.w = f2bf(b.z) | (f2bf(b.w) << 16);
        ((uint4*)d)[i] = u;
    }
}

// async global->LDS DMA, 16 B/lane. LDS dest = wave-uniform base + lane*16.
__device__ __forceinline__ void async_cp16(const void* g, void* l) {
    __builtin_amdgcn_global_load_lds(
        (__attribute__((address_space(1))) void*)g,
        (__attribute__((address_space(3))) void*)l,
        16, 0, 0);
}

// ---------------------------------------------------------------------------
// C[M,N] = A[M,K] @ B[N,K]^T, bf16 in, fp32 acc, bf16/fp32 out (R9/R10-proven)
// ---------------------------------------------------------------------------
template <bool C32>
__global__ __launch_bounds__(256)
void gemm_nt_dma(const ushort_t* __restrict__ A,
                 const ushort_t* __restrict__ B0,
                 const ushort_t* __restrict__ B1,
                 const ushort_t* __restrict__ B2,
                 void* __restrict__ C0,
                 void* __restrict__ C1,
                 void* __restrict__ C2) {
    const int z = blockIdx.z;
    const ushort_t* B = (z == 0) ? B0 : (z == 1) ? B1 : B2;
    void* C = (z == 0) ? C0 : (z == 1) ? C1 : C2;

    const int K = D_MODEL, N = D_MODEL;
    const int i0 = blockIdx.x * 128;
    const int n0 = blockIdx.y * 128;

    __shared__ __align__(16) ushort_t As[128 * 32];   // NO padding (DMA layout)
    __shared__ __align__(16) ushort_t Bs[128 * 32];

    const int t = threadIdx.x;
    const int w = t >> 6, lane = t & 63;
    const int wm = (w >> 1) * 64, wn = (w & 1) * 64;
    const int lr = lane & 15, lq = lane >> 4;

    const int srow = w * 16 + (lane >> 2);
    const int scol = (lane & 3) * 8;
    const ushort_t* gA0 = A + (size_t)(i0 + srow) * K + scol;
    const ushort_t* gA1 = A + (size_t)(i0 + 64 + srow) * K + scol;
    const ushort_t* gB0 = B + (size_t)(n0 + srow) * K + scol;
    const ushort_t* gB1 = B + (size_t)(n0 + 64 + srow) * K + scol;
    ushort_t* lA0 = &As[(w * 16) * 32];
    ushort_t* lA1 = &As[(64 + w * 16) * 32];
    ushort_t* lB0 = &Bs[(w * 16) * 32];
    ushort_t* lB1 = &Bs[(64 + w * 16) * 32];

    f32x4 acc[4][4];
#pragma unroll
    for (int a = 0; a < 4; a++)
#pragma unroll
        for (int b = 0; b < 4; b++) acc[a][b] = (f32x4){0.f, 0.f, 0.f, 0.f};

    for (int k0 = 0; k0 < K; k0 += 32) {
        __syncthreads();
        async_cp16(gA0 + k0, lA0);
        async_cp16(gA1 + k0, lA1);
        async_cp16(gB0 + k0, lB0);
        async_cp16(gB1 + k0, lB1);
        __builtin_amdgcn_s_waitcnt(0);
        __syncthreads();

        bf16x8 af[4], bfr[4];
#pragma unroll
        for (int mi = 0; mi < 4; mi++)
            af[mi] = *(const bf16x8*)&As[(wm + mi * 16 + lr) * 32 + lq * 8];
#pragma unroll
        for (int ni = 0; ni < 4; ni++)
            bfr[ni] = *(const bf16x8*)&Bs[(wn + ni * 16 + lr) * 32 + lq * 8];
#pragma unroll
        for (int mi = 0; mi < 4; mi++)
#pragma unroll
            for (int ni = 0; ni < 4; ni++)
                acc[mi][ni] = __builtin_amdgcn_mfma_f32_16x16x32_bf16(
                    af[mi], bfr[ni], acc[mi][ni], 0, 0, 0);
    }

    // C/D layout: col = lane&15, row = (lane>>4)*4 + reg
    if (C32) {
        float* Cf = (float*)C;
#pragma unroll
        for (int mi = 0; mi < 4; mi++)
#pragma unroll
            for (int ni = 0; ni < 4; ni++)
#pragma unroll
                for (int r = 0; r < 4; r++) {
                    int row = i0 + wm + mi * 16 + lq * 4 + r;
                    int col = n0 + wn + ni * 16 + lr;
                    Cf[(size_t)row * N + col] = acc[mi][ni][r];
                }
    } else {
        ushort_t* Cb = (ushort_t*)C;
#pragma unroll
        for (int mi = 0; mi < 4; mi++)
#pragma unroll
            for (int ni = 0; ni < 4; ni++)
#pragma unroll
                for (int r = 0; r < 4; r++) {
                    int row = i0 + wm + mi * 16 + lq * 4 + r;
                    int col = n0 + wn + ni * 16 + lr;
                    Cb[(size_t)row * N + col] = (ushort_t)f2bf(acc[mi][ni][r]);
                }
    }
}

// ---------------------------------------------------------------------------
// Build K LDS-images. Grid (93, 7). Image s<28: fano chunk (slots = compacted
// p = s*64+slot); s>=28: band window w_=s-28, j = w_*64-16+slot.
// Image layout = exactly the kernel's Ks LDS layout: [64 slots][LSK u16].
// OOR keys -> zeros.
// ---------------------------------------------------------------------------
__global__ __launch_bounds__(256)
void build_k_img(const ushort_t* __restrict__ Kb, ushort_t* __restrict__ Kimg) {
    const int s = blockIdx.x, h = blockIdx.y, t = threadIdx.x;
    const int slot = t >> 2, c0 = (t & 3) * 32;
    const int r0 = d_R[h][0], r1 = d_R[h][1], r2 = d_R[h][2];
    int j = (s < 28) ? jof(s * 64 + slot, r0, r1, r2)
                     : (s - 28) * 64 - 16 + slot;
    ushort_t* dst = Kimg + (size_t)(h * NIMG + s) * KIMG_U16 + slot * LSK + c0;
    if (j >= 0 && j < T_SEQ) {
        const ushort_t* src = Kb + (size_t)j * D_MODEL + h * 128 + c0;
#pragma unroll
        for (int v = 0; v < 4; v++)
            *(uint4*)(dst + v * 8) = *(const uint4*)(src + v * 8);
    } else {
        uint4 zz = {0u, 0u, 0u, 0u};
#pragma unroll
        for (int v = 0; v < 4; v++) *(uint4*)(dst + v * 8) = zz;
    }
}

// ---------------------------------------------------------------------------
// Build V LDS-images (transposed): image layout [128 dims][LSV u16], cols =
// key slots. Thread: dim = t>>1, half = t&1 covers slots [half*32, +32).
// The per-key gather + transpose cost is paid ONCE here instead of ~10x in
// the attention chunk loop.
// ---------------------------------------------------------------------------
__global__ __launch_bounds__(256)
void build_v_img(const ushort_t* __restrict__ Vb, ushort_t* __restrict__ Vimg) {
    const int s = blockIdx.x, h = blockIdx.y, t = threadIdx.x;
    const int d = t >> 1, half = t & 1;
    const int r0 = d_R[h][0], r1 = d_R[h][1], r2 = d_R[h][2];
    ushort_t tmp[32];
#pragma unroll
    for (int k = 0; k < 32; k++) {
        int slot = half * 32 + k;
        int j = (s < 28) ? jof(s * 64 + slot, r0, r1, r2)
                         : (s - 28) * 64 - 16 + slot;
        tmp[k] = (j >= 0 && j < T_SEQ)
                     ? Vb[(size_t)j * D_MODEL + h * 128 + d] : (ushort_t)0;
    }
    ushort_t* dst = Vimg + (size_t)(h * NIMG + s) * VIMG_U16 + d * LSV + half * 32;
#pragma unroll
    for (int v = 0; v < 4; v++)
        *(uint4*)(dst + v * 8) = *(const uint4*)&tmp[v * 8];
}

// ---------------------------------------------------------------------------
// Split-K MFMA Fano attention, image-DMA staging. Grid (64, 7, 4) x-reversed.
// Chunk staging = 35 contiguous global_load_lds dwordx4 (17 KB Ks + 18 KB Vt)
// from the pre-built images. Masks/softmax/PV identical to R10 (verified).
// ---------------------------------------------------------------------------
__global__ __launch_bounds__(256, 3)
void fano_attn_split(const ushort_t* __restrict__ Qb,
                     const ushort_t* __restrict__ Kimg,
                     const ushort_t* __restrict__ Vimg,
                     ushort_t* __restrict__ Opart,
                     float* __restrict__ Lm) {
    const int h = blockIdx.y;
    const int sp = blockIdx.z;
    const int tile = (int)gridDim.x - 1 - (int)blockIdx.x;  // LPT
    const int i0 = tile * 64;
    const int t = threadIdx.x;
    const int w = t >> 6, lane = t & 63;
    const int lr = lane & 15, quad = lane >> 4;
    const int iw0 = i0 + w * 16;

    __shared__ __align__(16) ushort_t Ks[64 * LSK];   // 17408 B
    __shared__ __align__(16) ushort_t Vt[128 * LSV];  // 18432 B
    __shared__ __align__(16) ushort_t Ps[64 * LSP];   //  9216 B

    const int r0 = d_R[h][0], r1 = d_R[h][1], r2 = d_R[h][2];
    const int lm = d_LINEMASK[h];
    const float scale = 0.08838834764831845f;

    // Q A-frags: lane holds Q[iw0+lr][f*32 + quad*8 + (0..7)]
    bf16x8 qf[4];
    {
        const ushort_t* qrow = Qb + (size_t)(iw0 + lr) * D_MODEL + h * 128;
#pragma unroll
        for (int f = 0; f < 4; f++)
            qf[f] = *(const bf16x8*)(qrow + f * 32 + quad * 8);
    }

    f32x4 O[8];
#pragma unroll
    for (int dt = 0; dt < 8; dt++) O[dt] = (f32x4){0.f, 0.f, 0.f, 0.f};
    float m[4] = {-1e30f, -1e30f, -1e30f, -1e30f};
    float l[4] = {0.f, 0.f, 0.f, 0.f};

    const int imax = i0 + 63;
    const int ncomp = (imax - r0) / 7 + (imax - r1) / 7 + (imax - r2) / 7 + 3;
    const int nch = (ncomp + 63) >> 6;
    const int ntot = nch + 2;                 // + two band windows
    const int cstart = (sp * ntot) / NSPLIT;
    const int cend = ((sp + 1) * ntot) / NSPLIT;

    for (int cc = cstart; cc < cend; cc++) {
        const bool band = (cc >= nch);
        const int base = band ? 0 : cc * 64;
        const int jbase = (cc == nch) ? i0 - 16 : i0 + 48;
        // image index: fano -> cc; band1 -> 28+tile; band2 -> 28+tile+1
        const int s = band ? (28 + tile + (cc - nch)) : cc;
        const ushort_t* kimg = Kimg + (size_t)(h * NIMG + s) * KIMG_U16;
        const ushort_t* vimg = Vimg + (size_t)(h * NIMG + s) * VIMG_U16;

        __syncthreads();   // prev chunk's LDS reads complete
        // DMA stage: Ks = 17 x 1KB, Vt = 18 x 1KB; wave w takes 4 each + tail
#pragma unroll
        for (int k = 0; k < 4; k++) {
            int off = (w * 4 + k) * 512;   // u16 units (1 KB)
            async_cp16(kimg + off + lane * 8, &Ks[off]);
        }
        if (w == 0) async_cp16(kimg + 16 * 512 + lane * 8, &Ks[16 * 512]);
#pragma unroll
        for (int k = 0; k < 4; k++) {
            int off = (w * 4 + k) * 512;
            async_cp16(vimg + off + lane * 8, &Vt[off]);
        }
        if (w < 2) async_cp16(vimg + (16 + w) * 512 + lane * 8, &Vt[(16 + w) * 512]);
        __builtin_amdgcn_s_waitcnt(0);   // DMA landed
        __syncthreads();

        // wave-uniform skip: chunk min j beyond this wave's rows
        {
            int jmin = band ? jbase : jof(base, r0, r1, r2);
            if (jmin > iw0 + 15) continue;
        }

        // S = Q K^T over 4 tiles of 16 keys
        f32x4 S[4];
#pragma unroll
        for (int tn = 0; tn < 4; tn++) S[tn] = (f32x4){0.f, 0.f, 0.f, 0.f};
#pragma unroll
        for (int f = 0; f < 4; f++) {
            bf16x8 kf[4];
#pragma unroll
            for (int tn = 0; tn < 4; tn++)
                kf[tn] = *(const bf16x8*)&Ks[(tn * 16 + lr) * LSK + f * 32 + quad * 8];
#pragma unroll
            for (int tn = 0; tn < 4; tn++)
                S[tn] = __builtin_amdgcn_mfma_f32_16x16x32_bf16(qf[f], kf[tn], S[tn], 0, 0, 0);
        }

        // mask. fano: j<=i. band: 0<=j<=i, j>=i-16, j%7 not in line (disjoint).
#pragma unroll
        for (int tn = 0; tn < 4; tn++) {
            int j;
            bool okl = true;
            if (band) {
                j = jbase + tn * 16 + lr;
                int jm = ((j % 7) + 7) % 7;
                okl = (j >= 0) && !((lm >> jm) & 1);
            } else {
                j = jof(base + tn * 16 + lr, r0, r1, r2);
            }
#pragma unroll
            for (int r = 0; r < 4; r++) {
                int ir = iw0 + quad * 4 + r;
                bool ok = okl && (j <= ir) && (!band || j >= ir - 16);
                S[tn][r] = ok ? S[tn][r] * scale : -1e30f;
            }
        }

        // online softmax (row = (quad, r); key-reduce across lr via shfl)
        float a4[4], pvv[4][4];
#pragma unroll
        for (int r = 0; r < 4; r++) {
            float cm = fmaxf(fmaxf(S[0][r], S[1][r]), fmaxf(S[2][r], S[3][r]));
            cm = fmaxf(cm, __shfl_xor(cm, 1));
            cm = fmaxf(cm, __shfl_xor(cm, 2));
            cm = fmaxf(cm, __shfl_xor(cm, 4));
            cm = fmaxf(cm, __shfl_xor(cm, 8));
            float mn = fmaxf(fmaxf(m[r], cm), -60.f);  // all-masked -> exact 0
            a4[r] = __expf(m[r] - mn);
            m[r] = mn;
            float rs_ = 0.f;
#pragma unroll
            for (int tn = 0; tn < 4; tn++) {
                pvv[tn][r] = __expf(S[tn][r] - mn);
                rs_ += pvv[tn][r];
            }
            rs_ += __shfl_xor(rs_, 1);
            rs_ += __shfl_xor(rs_, 2);
            rs_ += __shfl_xor(rs_, 4);
            rs_ += __shfl_xor(rs_, 8);
            l[r] = l[r] * a4[r] + rs_;
            ushort_t* pp = &Ps[(w * 16 + quad * 4 + r) * LSP + lr];
            pp[0]  = (ushort_t)f2bf(pvv[0][r]);
            pp[16] = (ushort_t)f2bf(pvv[1][r]);
            pp[32] = (ushort_t)f2bf(pvv[2][r]);
            pp[48] = (ushort_t)f2bf(pvv[3][r]);
        }
#pragma unroll
        for (int dt = 0; dt < 8; dt++)
#pragma unroll
            for (int r = 0; r < 4; r++) O[dt][r] *= a4[r];

        // P (A-frag via LDS round-trip, wave-private Ps rows) x Vt
        bf16x8 pf0 = *(const bf16x8*)&Ps[(w * 16 + lr) * LSP + quad * 8];
        bf16x8 pf1 = *(const bf16x8*)&Ps[(w * 16 + lr) * LSP + 32 + quad * 8];
#pragma unroll
        for (int dt = 0; dt < 8; dt++) {
            bf16x8 v0 = *(const bf16x8*)&Vt[(dt * 16 + lr) * LSV + quad * 8];
            bf16x8 v1 = *(const bf16x8*)&Vt[(dt * 16 + lr) * LSV + 32 + quad * 8];
            O[dt] = __builtin_amdgcn_mfma_f32_16x16x32_bf16(pf0, v0, O[dt], 0, 0, 0);
            O[dt] = __builtin_amdgcn_mfma_f32_16x16x32_bf16(pf1, v1, O[dt], 0, 0, 0);
        }
    }

    // write unnormalized partials
    const size_t pbase = ((size_t)sp * 7 + h) * T_SEQ;
#pragma unroll
    for (int dt = 0; dt < 8; dt++)
#pragma unroll
        for (int r = 0; r < 4; r++) {
            int row = iw0 + quad * 4 + r;
            Opart[(pbase + row) * 128 + dt * 16 + lr] = (ushort_t)f2bf(O[dt][r]);
        }
    if (lr == 0) {
#pragma unroll
        for (int r = 0; r < 4; r++) {
            int row = iw0 + quad * 4 + r;
            Lm[(pbase + row) * 2 + 0] = m[r];
            Lm[(pbase + row) * 2 + 1] = l[r];
        }
    }
}

// ---------------------------------------------------------------------------
// Merge NSPLIT partials -> Ab (bf16). Grid (64,7), block 256.
// ---------------------------------------------------------------------------
__global__ __launch_bounds__(256)
void attn_merge(const ushort_t* __restrict__ Opart,
                const float* __restrict__ Lm,
                ushort_t* __restrict__ Ab) {
    const int h = blockIdx.y;
    const int row = blockIdx.x * 64 + (threadIdx.x >> 2);
    const int d0 = (threadIdx.x & 3) * 32;

    float ms[NSPLIT], ls[NSPLIT], M = -1e30f;
#pragma unroll
    for (int s = 0; s < NSPLIT; s++) {
        size_t pb = (((size_t)s * 7 + h) * T_SEQ + row) * 2;
        ms[s] = Lm[pb];
        ls[s] = Lm[pb + 1];
        M = fmaxf(M, ms[s]);
    }
    float L = 0.f, c[NSPLIT];
#pragma unroll
    for (int s = 0; s < NSPLIT; s++) {
        c[s] = __expf(ms[s] - M);
        L += c[s] * ls[s];
    }
    float acc[32];
#pragma unroll
    for (int k = 0; k < 32; k++) acc[k] = 0.f;
#pragma unroll
    for (int s = 0; s < NSPLIT; s++) {
        const ushort_t* op = Opart + (((size_t)s * 7 + h) * T_SEQ + row) * 128 + d0;
#pragma unroll
        for (int v = 0; v < 4; v++) {
            uint4 u = *(const uint4*)(op + v * 8);
            acc[v * 8 + 0] += c[s] * lo_f(u.x);
            acc[v * 8 + 1] += c[s] * hi_f(u.x);
            acc[v * 8 + 2] += c[s] * lo_f(u.y);
            acc[v * 8 + 3] += c[s] * hi_f(u.y);
            acc[v * 8 + 4] += c[s] * lo_f(u.z);
            acc[v * 8 + 5] += c[s] * hi_f(u.z);
            acc[v * 8 + 6] += c[s] * lo_f(u.w);
            acc[v * 8 + 7] += c[s] * hi_f(u.w);
        }
    }
    float invL = 1.f / L;
    ushort_t* dst = Ab + (size_t)row * D_MODEL + h * 128 + d0;
#pragma unroll
    for (int v = 0; v < 4; v++) {
        uint4 u;
        u.x = f2bf(acc[v * 8 + 0] * invL) | (f2bf(acc[v * 8 + 1] * invL) << 16);
        u.y = f2bf(acc[v * 8 + 2] * invL) | (f2bf(acc[v * 8 + 3] * invL) << 16);
        u.z = f2bf(acc[v * 8 + 4] * invL) | (f2bf(acc[v * 8 + 5] * invL) << 16);
        u.w = f2bf(acc[v * 8 + 6] * invL) | (f2bf(acc[v * 8 + 7] * invL) << 16);
        *(uint4*)(dst + v * 8) = u;
    }
}

extern "C" void kernel_launch(void* const* d_in, const int* in_sizes, int n_in,
                              void* d_out, int out_size, void* d_ws, size_t ws_size,
                              hipStream_t stream) {
    const float* x  = (const float*)d_in[0];   // fp32 [4096, 896]
    const float* Wq = (const float*)d_in[1];   // fp32 [896, 896]
    const float* Wk = (const float*)d_in[2];
    const float* Wv = (const float*)d_in[3];
    const float* Wo = (const float*)d_in[4];

    const size_t n  = (size_t)T_SEQ * D_MODEL;
    const size_t nw = (size_t)D_MODEL * D_MODEL;
    ushort_t* xb  = (ushort_t*)d_ws + 128;   // 256B offset
    ushort_t* Wqb = xb + n;
    ushort_t* Wkb = Wqb + nw;
    ushort_t* Wvb = Wkb + nw;
    ushort_t* Wob = Wvb + nw;
    ushort_t* Qb  = Wob + nw;
    ushort_t* Kb  = Qb + n;
    ushort_t* Vb  = Kb + n;
    ushort_t* Ab  = Vb + n;
    ushort_t* Opart = Ab + n;                          // 4*7*4096*128 bf16
    float*    Lm  = (float*)(Opart + (size_t)NSPLIT * 7 * T_SEQ * 128);
    ushort_t* Kimg = (ushort_t*)(Lm + (size_t)NSPLIT * 7 * T_SEQ * 2);
    ushort_t* Vimg = Kimg + (size_t)7 * NIMG * KIMG_U16;

    // 0: fp32 -> bf16 bulk convert (x + 4 weights)
    cvt5<<<dim3(1792, 5), 256, 0, stream>>>(x, Wq, Wk, Wv, Wo,
                                            xb, Wqb, Wkb, Wvb, Wob);
    // 1: Q/K/V = x @ W^T (bf16, DMA-staged)
    gemm_nt_dma<false><<<dim3(32, 7, 3), 256, 0, stream>>>(
        xb, Wqb, Wkb, Wvb, Qb, Kb, Vb);
    // 2: build K/V LDS-images (fano compaction + V transpose, done ONCE)
    build_k_img<<<dim3(NIMG, 7), 256, 0, stream>>>(Kb, Kimg);
    build_v_img<<<dim3(NIMG, 7), 256, 0, stream>>>(Vb, Vimg);
    // 3: split-K sparse attention (DMA image staging) -> partials
    fano_attn_split<<<dim3(64, 7, NSPLIT), 256, 0, stream>>>(
        Qb, Kimg, Vimg, Opart, Lm);
    // 4: merge partials -> Ab
    attn_merge<<<dim3(64, 7), 256, 0, stream>>>(Opart, Lm, Ab);
    // 5: out = Ab @ Wo^T -> fp32
    gemm_nt_dma<true><<<dim3(32, 7, 1), 256, 0, stream>>>(
        Ab, Wob, Wob, Wob, d_out, d_out, d_out);
}